// Round 1
// baseline (11068.726 us; speedup 1.0000x reference)
//
#include <hip/hip_runtime.h>

// GIN x3 + BN + global mean pool + MLP head, fp32.
// BN is folded into consumers as affine (scale, shift) computed by bn_finalize.

#define TF1 5
#define TF2 10
#define TGD 10
#define BN_EPS 1e-5f

// ---------------- edge aggregation: agg[dst] += affine(h[src]) ----------------
template<int F, bool BN>
__global__ __launch_bounds__(256) void edge_agg_k(
    const int* __restrict__ ei, const float* __restrict__ h,
    const float* __restrict__ ss, float* __restrict__ agg, int E) {
  int e = blockIdx.x * blockDim.x + threadIdx.x;
  if (e >= E) return;
  int s = ei[e];
  int d = ei[E + e];
  #pragma unroll
  for (int f = 0; f < F; ++f) {
    float v = h[(long)s * F + f];
    if (BN) v = v * ss[f] + ss[F + f];
    atomicAdd(&agg[(long)d * F + f], v);
  }
}

// ---------------- node MLP: hout = relu(mlp(affine(h)+agg)), + BN stats ----------------
template<int FIN, int FHID, int FOUT, bool BN>
__global__ __launch_bounds__(256) void node_mlp_k(
    const float* __restrict__ h, const float* __restrict__ agg,
    const float* __restrict__ ssin,
    const float* __restrict__ w1, const float* __restrict__ b1,
    const float* __restrict__ w2, const float* __restrict__ b2,
    float* __restrict__ hout, double* __restrict__ stats, int Nn) {
  __shared__ float sw1[FIN * FHID], sb1[FHID], sw2[FHID * FOUT], sb2[FOUT];
  for (int i = threadIdx.x; i < FIN * FHID; i += blockDim.x) sw1[i] = w1[i];
  for (int i = threadIdx.x; i < FHID * FOUT; i += blockDim.x) sw2[i] = w2[i];
  if (threadIdx.x < FHID) sb1[threadIdx.x] = b1[threadIdx.x];
  if (threadIdx.x < FOUT) sb2[threadIdx.x] = b2[threadIdx.x];
  __syncthreads();

  float psum[FOUT], psq[FOUT];
  #pragma unroll
  for (int j = 0; j < FOUT; ++j) { psum[j] = 0.f; psq[j] = 0.f; }

  int i = blockIdx.x * blockDim.x + threadIdx.x;
  if (i < Nn) {
    float xin[FIN];
    #pragma unroll
    for (int f = 0; f < FIN; ++f) {
      float v = h[(long)i * FIN + f];
      if (BN) v = v * ssin[f] + ssin[FIN + f];
      xin[f] = v + agg[(long)i * FIN + f];
    }
    float u[FHID];
    #pragma unroll
    for (int j = 0; j < FHID; ++j) {
      float a = sb1[j];
      #pragma unroll
      for (int f = 0; f < FIN; ++f) a += xin[f] * sw1[f * FHID + j];
      u[j] = fmaxf(a, 0.f);
    }
    #pragma unroll
    for (int j = 0; j < FOUT; ++j) {
      float a = sb2[j];
      #pragma unroll
      for (int k = 0; k < FHID; ++k) a += u[k] * sw2[k * FOUT + j];
      float r = fmaxf(a, 0.f);
      hout[(long)i * FOUT + j] = r;
      psum[j] = r;
      psq[j] = r * r;
    }
  }

  // wave-level reduce (64 lanes), one double atomic per wave per feature
  int lane = threadIdx.x & 63;
  #pragma unroll
  for (int j = 0; j < FOUT; ++j) {
    float a = psum[j], b = psq[j];
    #pragma unroll
    for (int o = 32; o > 0; o >>= 1) {
      a += __shfl_down(a, o);
      b += __shfl_down(b, o);
    }
    if (lane == 0) {
      atomicAdd(&stats[j], (double)a);
      atomicAdd(&stats[FOUT + j], (double)b);
    }
  }
}

// ---------------- BN finalize: scale/shift from sums ----------------
__global__ void bn_finalize_k(const double* __restrict__ stats,
                              const float* __restrict__ gamma,
                              const float* __restrict__ beta,
                              float* __restrict__ ss, int F, double invN) {
  int f = threadIdx.x;
  if (f < F) {
    float mu = (float)(stats[f] * invN);
    float ex2 = (float)(stats[F + f] * invN);
    float var = ex2 - mu * mu;
    float rstd = rsqrtf(var + BN_EPS);
    float sc = rstd * gamma[f];
    ss[f] = sc;
    ss[F + f] = beta[f] - mu * sc;
  }
}

// ---------------- pooling: pooled[batch[i]] += affine(h[i]); cnt[batch[i]] += 1 ----------------
__global__ __launch_bounds__(256) void pool_k(
    const float* __restrict__ h, const float* __restrict__ ss,
    const int* __restrict__ batch, float* __restrict__ pooled,
    float* __restrict__ cnt, int Nn) {
  int i = blockIdx.x * blockDim.x + threadIdx.x;
  if (i >= Nn) return;
  int g = batch[i];
  #pragma unroll
  for (int f = 0; f < TF2; ++f) {
    float v = h[(long)i * TF2 + f] * ss[f] + ss[TF2 + f];
    atomicAdd(&pooled[(long)g * TF2 + f], v);
  }
  atomicAdd(&cnt[g], 1.0f);
}

// ---------------- head MLP: 20 -> 128 -> 64 -> 1, one block per graph ----------------
__global__ __launch_bounds__(128) void final_mlp_k(
    const float* __restrict__ pooled, const float* __restrict__ cnt,
    const float* __restrict__ gx,
    const float* __restrict__ fw1, const float* __restrict__ fb1,
    const float* __restrict__ fw2, const float* __restrict__ fb2,
    const float* __restrict__ fw3, const float* __restrict__ fb3,
    float* __restrict__ out) {
  int g = blockIdx.x;
  int t = threadIdx.x;  // 128
  __shared__ float z[TF2 + TGD];
  __shared__ float h1[128];
  __shared__ float h2[64];
  if (t < TF2) z[t] = pooled[(long)g * TF2 + t] / fmaxf(cnt[g], 1.f);
  else if (t < TF2 + TGD) z[t] = gx[(long)g * TGD + (t - TF2)];
  __syncthreads();
  {
    float a = fb1[t];
    #pragma unroll
    for (int i = 0; i < TF2 + TGD; ++i) a += z[i] * fw1[i * 128 + t];
    h1[t] = fmaxf(a, 0.f);
  }
  __syncthreads();
  if (t < 64) {
    float a = fb2[t];
    #pragma unroll 8
    for (int i = 0; i < 128; ++i) a += h1[i] * fw2[i * 64 + t];
    h2[t] = fmaxf(a, 0.f);
  }
  __syncthreads();
  if (t == 0) {
    float a = fb3[0];
    #pragma unroll 8
    for (int i = 0; i < 64; ++i) a += h2[i] * fw3[i];
    out[g] = a;
  }
}

extern "C" void kernel_launch(void* const* d_in, const int* in_sizes, int n_in,
                              void* d_out, int out_size, void* d_ws, size_t ws_size,
                              hipStream_t stream) {
  const float* x      = (const float*)d_in[0];
  const int*   ei     = (const int*)d_in[1];
  const int*   batch  = (const int*)d_in[2];
  const float* gx     = (const float*)d_in[3];
  const float* w11 = (const float*)d_in[4],  *b11 = (const float*)d_in[5];
  const float* w12 = (const float*)d_in[6],  *b12 = (const float*)d_in[7];
  const float* w21 = (const float*)d_in[8],  *b21 = (const float*)d_in[9];
  const float* w22 = (const float*)d_in[10], *b22 = (const float*)d_in[11];
  const float* w31 = (const float*)d_in[12], *b31 = (const float*)d_in[13];
  const float* w32 = (const float*)d_in[14], *b32 = (const float*)d_in[15];
  const float* g1  = (const float*)d_in[16], *be1 = (const float*)d_in[17];
  const float* g2  = (const float*)d_in[18], *be2 = (const float*)d_in[19];
  const float* g3  = (const float*)d_in[20], *be3 = (const float*)d_in[21];
  const float* fw1 = (const float*)d_in[22], *fb1 = (const float*)d_in[23];
  const float* fw2 = (const float*)d_in[24], *fb2 = (const float*)d_in[25];
  const float* fw3 = (const float*)d_in[26], *fb3 = (const float*)d_in[27];

  const int N = in_sizes[0] / TF1;
  const int E = in_sizes[1] / 2;
  const int G = in_sizes[3] / TGD;

  // workspace layout
  char* ws = (char*)d_ws;
  float* agg = (float*)ws;  ws += (size_t)N * TF2 * sizeof(float);
  float* hA  = (float*)ws;  ws += (size_t)N * TF2 * sizeof(float);
  float* hB  = (float*)ws;  ws += (size_t)N * TF2 * sizeof(float);
  // zero-region start: stats (doubles first for alignment), then ss, pooled, cnt
  char* zstart = ws;
  double* st1 = (double*)ws; ws += 2 * TF2 * sizeof(double);
  double* st2 = (double*)ws; ws += 2 * TF2 * sizeof(double);
  double* st3 = (double*)ws; ws += 2 * TF2 * sizeof(double);
  float* ss1 = (float*)ws;   ws += 2 * TF2 * sizeof(float);
  float* ss2 = (float*)ws;   ws += 2 * TF2 * sizeof(float);
  float* ss3 = (float*)ws;   ws += 2 * TF2 * sizeof(float);
  float* pooled = (float*)ws; ws += (size_t)G * TF2 * sizeof(float);
  float* cnt = (float*)ws;    ws += (size_t)G * sizeof(float);
  size_t zbytes = (size_t)(ws - zstart);

  float* out = (float*)d_out;

  const int TB = 256;
  const int egrid = (E + TB - 1) / TB;
  const int ngrid = (N + TB - 1) / TB;
  const double invN = 1.0 / (double)N;

  hipMemsetAsync(zstart, 0, zbytes, stream);

  // ---- layer 1 (5 -> 5 -> 5), no input BN ----
  hipMemsetAsync(agg, 0, (size_t)N * TF1 * sizeof(float), stream);
  edge_agg_k<TF1, false><<<egrid, TB, 0, stream>>>(ei, x, nullptr, agg, E);
  node_mlp_k<TF1, TF1, TF1, false><<<ngrid, TB, 0, stream>>>(
      x, agg, nullptr, w11, b11, w12, b12, hA, st1, N);
  bn_finalize_k<<<1, 64, 0, stream>>>(st1, g1, be1, ss1, TF1, invN);

  // ---- layer 2 (5 -> 10 -> 10), input BN = ss1 ----
  hipMemsetAsync(agg, 0, (size_t)N * TF1 * sizeof(float), stream);
  edge_agg_k<TF1, true><<<egrid, TB, 0, stream>>>(ei, hA, ss1, agg, E);
  node_mlp_k<TF1, TF2, TF2, true><<<ngrid, TB, 0, stream>>>(
      hA, agg, ss1, w21, b21, w22, b22, hB, st2, N);
  bn_finalize_k<<<1, 64, 0, stream>>>(st2, g2, be2, ss2, TF2, invN);

  // ---- layer 3 (10 -> 10 -> 10), input BN = ss2 ----
  hipMemsetAsync(agg, 0, (size_t)N * TF2 * sizeof(float), stream);
  edge_agg_k<TF2, true><<<egrid, TB, 0, stream>>>(ei, hB, ss2, agg, E);
  node_mlp_k<TF2, TF2, TF2, true><<<ngrid, TB, 0, stream>>>(
      hB, agg, ss2, w31, b31, w32, b32, hA, st3, N);
  bn_finalize_k<<<1, 64, 0, stream>>>(st3, g3, be3, ss3, TF2, invN);

  // ---- pool + head ----
  pool_k<<<ngrid, TB, 0, stream>>>(hA, ss3, batch, pooled, cnt, N);
  final_mlp_k<<<G, 128, 0, stream>>>(pooled, cnt, gx, fw1, fb1, fw2, fb2,
                                     fw3, fb3, out);
}

// Round 5
// 3875.318 us; speedup vs baseline: 2.8562x; 2.8562x over previous
//
#include <hip/hip_runtime.h>

// GIN x3 + BN + global mean pool + MLP head, fp32.
// Strategy: build dst-CSR once per launch (atomic cost ~1/10 of scatter path),
// then gather-based aggregation fused with node MLP + BN stats.
// BN folded into consumers as affine (scale, shift).

#define TF1 5
#define TF2 10
#define TGD 10
#define BN_EPS 1e-5f

// ---------------- row loader (vectorized where stride permits) ----------------
template<int FIN, int FINS>
__device__ __forceinline__ void load_row(const float* __restrict__ h, long idx,
                                         float (&v)[FIN]) {
  const float* p = h + idx * FINS;
  if constexpr (FIN == 5 && FINS == 8) {
    float4 a = *(const float4*)p;
    v[0] = a.x; v[1] = a.y; v[2] = a.z; v[3] = a.w; v[4] = p[4];
  } else if constexpr (FIN == 10 && FINS == 10) {
    #pragma unroll
    for (int k = 0; k < 5; ++k) {
      float2 a = *(const float2*)(p + 2 * k);
      v[2 * k] = a.x; v[2 * k + 1] = a.y;
    }
  } else {
    #pragma unroll
    for (int f = 0; f < FIN; ++f) v[f] = p[f];
  }
}

// ---------------- CSR build ----------------
__global__ __launch_bounds__(256) void degree_k(const int* __restrict__ ei,
                                                int* __restrict__ deg, int E) {
  int e = blockIdx.x * blockDim.x + threadIdx.x;
  if (e >= E) return;
  atomicAdd(&deg[ei[E + e]], 1);
}

// block-local exclusive scan, 2048 elems/block (256 thr x 8)
__global__ __launch_bounds__(256) void scan1_k(const int* __restrict__ deg,
                                               int* __restrict__ exc,
                                               int* __restrict__ bsum, int n) {
  __shared__ int lds[256];
  int t = threadIdx.x;
  int base = blockIdx.x * 2048 + t * 8;
  int v[8]; int local = 0;
  #pragma unroll
  for (int k = 0; k < 8; ++k) {
    int idx = base + k;
    v[k] = (idx < n) ? deg[idx] : 0;
    local += v[k];
  }
  lds[t] = local;
  __syncthreads();
  for (int off = 1; off < 256; off <<= 1) {
    int x = (t >= off) ? lds[t - off] : 0;
    __syncthreads();
    lds[t] += x;
    __syncthreads();
  }
  int running = lds[t] - local;  // exclusive prefix of this thread's chunk
  #pragma unroll
  for (int k = 0; k < 8; ++k) {
    int idx = base + k;
    if (idx < n) exc[idx] = running;
    running += v[k];
  }
  if (t == 255) bsum[blockIdx.x] = lds[255];
}

__global__ __launch_bounds__(256) void scan2_k(int* __restrict__ bsum, int nb) {
  __shared__ int lds[256];
  int t = threadIdx.x;
  int v = (t < nb) ? bsum[t] : 0;
  lds[t] = v;
  __syncthreads();
  for (int off = 1; off < 256; off <<= 1) {
    int x = (t >= off) ? lds[t - off] : 0;
    __syncthreads();
    lds[t] += x;
    __syncthreads();
  }
  if (t < nb) bsum[t] = lds[t] - v;  // exclusive
}

__global__ __launch_bounds__(256) void scan3_k(int* __restrict__ exc,
                                               const int* __restrict__ bsum,
                                               int n) {
  int i = blockIdx.x * blockDim.x + threadIdx.x;
  if (i < n) exc[i] += bsum[i >> 11];
}

__global__ __launch_bounds__(256) void place_k(const int* __restrict__ ei,
                                               int* __restrict__ cursor,
                                               int* __restrict__ colidx, int E) {
  int e = blockIdx.x * blockDim.x + threadIdx.x;
  if (e >= E) return;
  int s = ei[e];
  int d = ei[E + e];
  int pos = atomicAdd(&cursor[d], 1);
  colidx[pos] = s;
}

// ---------------- fallback scatter aggregation (small-ws path) ----------------
template<int F, bool BN>
__global__ __launch_bounds__(256) void edge_agg_k(
    const int* __restrict__ ei, const float* __restrict__ h,
    const float* __restrict__ ss, float* __restrict__ agg, int E) {
  int e = blockIdx.x * blockDim.x + threadIdx.x;
  if (e >= E) return;
  int s = ei[e];
  int d = ei[E + e];
  #pragma unroll
  for (int f = 0; f < F; ++f) {
    float v = h[(long)s * F + f];
    if (BN) v = v * ss[f] + ss[F + f];
    atomicAdd(&agg[(long)d * F + f], v);
  }
}

// ---------------- fused GIN layer: aggregate + MLP + BN stats ----------------
template<int FIN, int FINS, int FHID, int FOUT, int FOUTS, bool BN, bool GATHER>
__global__ __launch_bounds__(256) void gin_k(
    const float* __restrict__ h, const float* __restrict__ agg,
    const int* __restrict__ deg, const int* __restrict__ rowend,
    const int* __restrict__ colidx, const float* __restrict__ ssin,
    const float* __restrict__ w1, const float* __restrict__ b1,
    const float* __restrict__ w2, const float* __restrict__ b2,
    float* __restrict__ hout, double* __restrict__ stats, int Nn) {
  __shared__ float sw1[FIN * FHID], sb1[FHID], sw2[FHID * FOUT], sb2[FOUT];
  for (int i = threadIdx.x; i < FIN * FHID; i += blockDim.x) sw1[i] = w1[i];
  for (int i = threadIdx.x; i < FHID * FOUT; i += blockDim.x) sw2[i] = w2[i];
  if (threadIdx.x < FHID) sb1[threadIdx.x] = b1[threadIdx.x];
  if (threadIdx.x < FOUT) sb2[threadIdx.x] = b2[threadIdx.x];
  __syncthreads();

  float psum[FOUT], psq[FOUT];
  #pragma unroll
  for (int j = 0; j < FOUT; ++j) { psum[j] = 0.f; psq[j] = 0.f; }

  int i = blockIdx.x * blockDim.x + threadIdx.x;
  if (i < Nn) {
    float acc[FIN];
    load_row<FIN, FINS>(h, i, acc);
    float xin[FIN];
    if constexpr (GATHER) {
      int end = rowend[i];
      int d = deg[i];
      for (int p = end - d; p < end; ++p) {
        int s = colidx[p];
        float t[FIN];
        load_row<FIN, FINS>(h, s, t);
        #pragma unroll
        for (int f = 0; f < FIN; ++f) acc[f] += t[f];
      }
      #pragma unroll
      for (int f = 0; f < FIN; ++f) {
        if (BN) xin[f] = acc[f] * ssin[f] + (float)(d + 1) * ssin[FIN + f];
        else    xin[f] = acc[f];
      }
    } else {
      #pragma unroll
      for (int f = 0; f < FIN; ++f) {
        float v = acc[f];
        if (BN) v = v * ssin[f] + ssin[FIN + f];
        xin[f] = v + agg[(long)i * FIN + f];
      }
    }
    float u[FHID];
    #pragma unroll
    for (int j = 0; j < FHID; ++j) {
      float a = sb1[j];
      #pragma unroll
      for (int f = 0; f < FIN; ++f) a += xin[f] * sw1[f * FHID + j];
      u[j] = fmaxf(a, 0.f);
    }
    #pragma unroll
    for (int j = 0; j < FOUT; ++j) {
      float a = sb2[j];
      #pragma unroll
      for (int k = 0; k < FHID; ++k) a += u[k] * sw2[k * FOUT + j];
      float r = fmaxf(a, 0.f);
      hout[(long)i * FOUTS + j] = r;
      psum[j] = r;
      psq[j] = r * r;
    }
  }

  int lane = threadIdx.x & 63;
  #pragma unroll
  for (int j = 0; j < FOUT; ++j) {
    float a = psum[j], b = psq[j];
    #pragma unroll
    for (int o = 32; o > 0; o >>= 1) {
      a += __shfl_down(a, o);
      b += __shfl_down(b, o);
    }
    if (lane == 0) {
      atomicAdd(&stats[j], (double)a);
      atomicAdd(&stats[FOUT + j], (double)b);
    }
  }
}

// ---------------- BN finalize ----------------
__global__ void bn_finalize_k(const double* __restrict__ stats,
                              const float* __restrict__ gamma,
                              const float* __restrict__ beta,
                              float* __restrict__ ss, int F, double invN) {
  int f = threadIdx.x;
  if (f < F) {
    float mu = (float)(stats[f] * invN);
    float ex2 = (float)(stats[F + f] * invN);
    float var = ex2 - mu * mu;
    float rstd = rsqrtf(var + BN_EPS);
    float sc = rstd * gamma[f];
    ss[f] = sc;
    ss[F + f] = beta[f] - mu * sc;
  }
}

// ---------------- pooling: batch is SORTED -> wave per graph, binary search ----------------
__global__ __launch_bounds__(256) void pool_k(
    const float* __restrict__ h, const float* __restrict__ ss,
    const int* __restrict__ batch, float* __restrict__ z, int Nn, int Gn) {
  int g = blockIdx.x * 4 + (threadIdx.x >> 6);
  if (g >= Gn) return;
  int lane = threadIdx.x & 63;
  // lower_bound(batch, g) and lower_bound(batch, g+1)
  int lo = 0, hi = Nn;
  while (lo < hi) { int m = (lo + hi) >> 1; if (batch[m] < g) lo = m + 1; else hi = m; }
  int start = lo;
  hi = Nn;
  while (lo < hi) { int m = (lo + hi) >> 1; if (batch[m] < g + 1) lo = m + 1; else hi = m; }
  int end = lo;

  float acc[TF2];
  #pragma unroll
  for (int f = 0; f < TF2; ++f) acc[f] = 0.f;
  for (int i = start + lane; i < end; i += 64) {
    #pragma unroll
    for (int f = 0; f < TF2; ++f) acc[f] += h[(long)i * TF2 + f];
  }
  #pragma unroll
  for (int f = 0; f < TF2; ++f) {
    #pragma unroll
    for (int o = 32; o > 0; o >>= 1) acc[f] += __shfl_down(acc[f], o);
  }
  if (lane == 0) {
    int cnt = end - start;
    float inv = cnt > 0 ? 1.f / (float)cnt : 0.f;
    #pragma unroll
    for (int f = 0; f < TF2; ++f) {
      float m = acc[f] * inv;
      z[(long)g * TF2 + f] = cnt > 0 ? m * ss[f] + ss[TF2 + f] : 0.f;
    }
  }
}

// ---------------- head MLP: 20 -> 128 -> 64 -> 1, one block per graph ----------------
__global__ __launch_bounds__(128) void final_mlp_k(
    const float* __restrict__ z10, const float* __restrict__ gx,
    const float* __restrict__ fw1, const float* __restrict__ fb1,
    const float* __restrict__ fw2, const float* __restrict__ fb2,
    const float* __restrict__ fw3, const float* __restrict__ fb3,
    float* __restrict__ out) {
  int g = blockIdx.x;
  int t = threadIdx.x;  // 128
  __shared__ float z[TF2 + TGD];
  __shared__ float h1[128];
  __shared__ float h2[64];
  if (t < TF2) z[t] = z10[(long)g * TF2 + t];
  else if (t < TF2 + TGD) z[t] = gx[(long)g * TGD + (t - TF2)];
  __syncthreads();
  {
    float a = fb1[t];
    #pragma unroll
    for (int i = 0; i < TF2 + TGD; ++i) a += z[i] * fw1[i * 128 + t];
    h1[t] = fmaxf(a, 0.f);
  }
  __syncthreads();
  if (t < 64) {
    float a = fb2[t];
    #pragma unroll 8
    for (int i = 0; i < 128; ++i) a += h1[i] * fw2[i * 64 + t];
    h2[t] = fmaxf(a, 0.f);
  }
  __syncthreads();
  if (t == 0) {
    float a = fb3[0];
    #pragma unroll 8
    for (int i = 0; i < 64; ++i) a += h2[i] * fw3[i];
    out[g] = a;
  }
}

extern "C" void kernel_launch(void* const* d_in, const int* in_sizes, int n_in,
                              void* d_out, int out_size, void* d_ws, size_t ws_size,
                              hipStream_t stream) {
  const float* x      = (const float*)d_in[0];
  const int*   ei     = (const int*)d_in[1];
  const int*   batch  = (const int*)d_in[2];
  const float* gx     = (const float*)d_in[3];
  const float* w11 = (const float*)d_in[4],  *b11 = (const float*)d_in[5];
  const float* w12 = (const float*)d_in[6],  *b12 = (const float*)d_in[7];
  const float* w21 = (const float*)d_in[8],  *b21 = (const float*)d_in[9];
  const float* w22 = (const float*)d_in[10], *b22 = (const float*)d_in[11];
  const float* w31 = (const float*)d_in[12], *b31 = (const float*)d_in[13];
  const float* w32 = (const float*)d_in[14], *b32 = (const float*)d_in[15];
  const float* g1  = (const float*)d_in[16], *be1 = (const float*)d_in[17];
  const float* g2  = (const float*)d_in[18], *be2 = (const float*)d_in[19];
  const float* g3  = (const float*)d_in[20], *be3 = (const float*)d_in[21];
  const float* fw1 = (const float*)d_in[22], *fb1 = (const float*)d_in[23];
  const float* fw2 = (const float*)d_in[24], *fb2 = (const float*)d_in[25];
  const float* fw3 = (const float*)d_in[26], *fb3 = (const float*)d_in[27];

  const int N = in_sizes[0] / TF1;
  const int E = in_sizes[1] / 2;
  const int G = in_sizes[3] / TGD;

  float* out = (float*)d_out;
  const int TB = 256;
  const int egrid = (E + TB - 1) / TB;
  const int ngrid = (N + TB - 1) / TB;
  const int pgrid = (G + 3) / 4;
  const double invN = 1.0 / (double)N;

  // ---- CSR-path workspace ----
  size_t need_hA   = (size_t)N * 10 * 4;   // layer1 out (stride 8) / layer3 out (stride 10)
  size_t need_hB   = (size_t)N * 10 * 4;   // layer2 out (stride 10)
  size_t need_col  = (size_t)E * 4;
  size_t need_deg  = (size_t)N * 4;
  size_t need_cur  = (size_t)N * 4;
  size_t need_bsum = 4096;
  size_t small     = 3 * 2 * TF2 * sizeof(double) + 3 * 2 * TF2 * sizeof(float)
                   + (size_t)G * TF2 * sizeof(float) + 1024;
  size_t need_csr  = need_hA + need_hB + need_col + need_deg + need_cur + need_bsum + small;

  if (ws_size >= need_csr) {
    char* ws = (char*)d_ws;
    float* hA = (float*)ws;   ws += need_hA;
    float* hB = (float*)ws;   ws += need_hB;
    int* colidx = (int*)ws;   ws += need_col;
    int* deg = (int*)ws;      ws += need_deg;
    int* cursor = (int*)ws;   ws += need_cur;
    int* bsum = (int*)ws;     ws += need_bsum;
    double* st1 = (double*)ws; ws += 2 * TF2 * sizeof(double);
    double* st2 = (double*)ws; ws += 2 * TF2 * sizeof(double);
    double* st3 = (double*)ws; ws += 2 * TF2 * sizeof(double);
    float* ss1 = (float*)ws;   ws += 2 * TF2 * sizeof(float);
    float* ss2 = (float*)ws;   ws += 2 * TF2 * sizeof(float);
    float* ss3 = (float*)ws;   ws += 2 * TF2 * sizeof(float);
    float* z   = (float*)ws;

    hipMemsetAsync(deg, 0, need_deg, stream);
    hipMemsetAsync(st1, 0, 3 * 2 * TF2 * sizeof(double), stream);

    // CSR build
    degree_k<<<egrid, TB, 0, stream>>>(ei, deg, E);
    int nb = (N + 2047) / 2048;
    scan1_k<<<nb, TB, 0, stream>>>(deg, cursor, bsum, N);
    scan2_k<<<1, TB, 0, stream>>>(bsum, nb);
    scan3_k<<<ngrid, TB, 0, stream>>>(cursor, bsum, N);
    place_k<<<egrid, TB, 0, stream>>>(ei, cursor, colidx, E);
    // after place_k: cursor[i] == row end of node i

    // layer 1: 5 -> 5 -> 5, no input BN; out stride 8
    gin_k<TF1, TF1, TF1, TF1, 8, false, true><<<ngrid, TB, 0, stream>>>(
        x, nullptr, deg, cursor, colidx, nullptr, w11, b11, w12, b12, hA, st1, N);
    bn_finalize_k<<<1, 64, 0, stream>>>(st1, g1, be1, ss1, TF1, invN);

    // layer 2: 5 -> 10 -> 10, input BN ss1; in stride 8, out stride 10
    gin_k<TF1, 8, TF2, TF2, TF2, true, true><<<ngrid, TB, 0, stream>>>(
        hA, nullptr, deg, cursor, colidx, ss1, w21, b21, w22, b22, hB, st2, N);
    bn_finalize_k<<<1, 64, 0, stream>>>(st2, g2, be2, ss2, TF2, invN);

    // layer 3: 10 -> 10 -> 10, input BN ss2
    gin_k<TF2, TF2, TF2, TF2, TF2, true, true><<<ngrid, TB, 0, stream>>>(
        hB, nullptr, deg, cursor, colidx, ss2, w31, b31, w32, b32, hA, st3, N);
    bn_finalize_k<<<1, 64, 0, stream>>>(st3, g3, be3, ss3, TF2, invN);

    pool_k<<<pgrid, TB, 0, stream>>>(hA, ss3, batch, z, N, G);
    final_mlp_k<<<G, 128, 0, stream>>>(z, gx, fw1, fb1, fw2, fb2, fw3, fb3, out);
  } else {
    // ---- fallback: scatter-atomic path (round-1 scheme) ----
    char* ws = (char*)d_ws;
    float* agg = (float*)ws;  ws += (size_t)N * TF2 * sizeof(float);
    float* hA  = (float*)ws;  ws += (size_t)N * TF2 * sizeof(float);
    float* hB  = (float*)ws;  ws += (size_t)N * TF2 * sizeof(float);
    double* st1 = (double*)ws; ws += 2 * TF2 * sizeof(double);
    double* st2 = (double*)ws; ws += 2 * TF2 * sizeof(double);
    double* st3 = (double*)ws; ws += 2 * TF2 * sizeof(double);
    float* ss1 = (float*)ws;   ws += 2 * TF2 * sizeof(float);
    float* ss2 = (float*)ws;   ws += 2 * TF2 * sizeof(float);
    float* ss3 = (float*)ws;   ws += 2 * TF2 * sizeof(float);
    float* z   = (float*)ws;

    hipMemsetAsync(st1, 0, 3 * 2 * TF2 * sizeof(double), stream);

    hipMemsetAsync(agg, 0, (size_t)N * TF1 * sizeof(float), stream);
    edge_agg_k<TF1, false><<<egrid, TB, 0, stream>>>(ei, x, nullptr, agg, E);
    gin_k<TF1, TF1, TF1, TF1, TF1, false, false><<<ngrid, TB, 0, stream>>>(
        x, agg, nullptr, nullptr, nullptr, nullptr, w11, b11, w12, b12, hA, st1, N);
    bn_finalize_k<<<1, 64, 0, stream>>>(st1, g1, be1, ss1, TF1, invN);

    hipMemsetAsync(agg, 0, (size_t)N * TF1 * sizeof(float), stream);
    edge_agg_k<TF1, true><<<egrid, TB, 0, stream>>>(ei, hA, ss1, agg, E);
    gin_k<TF1, TF1, TF2, TF2, TF2, true, false><<<ngrid, TB, 0, stream>>>(
        hA, agg, nullptr, nullptr, nullptr, ss1, w21, b21, w22, b22, hB, st2, N);
    bn_finalize_k<<<1, 64, 0, stream>>>(st2, g2, be2, ss2, TF2, invN);

    hipMemsetAsync(agg, 0, (size_t)N * TF2 * sizeof(float), stream);
    edge_agg_k<TF2, true><<<egrid, TB, 0, stream>>>(ei, hB, ss2, agg, E);
    gin_k<TF2, TF2, TF2, TF2, TF2, true, false><<<ngrid, TB, 0, stream>>>(
        hB, agg, nullptr, nullptr, nullptr, ss2, w31, b31, w32, b32, hA, st3, N);
    bn_finalize_k<<<1, 64, 0, stream>>>(st3, g3, be3, ss3, TF2, invN);

    pool_k<<<pgrid, TB, 0, stream>>>(hA, ss3, batch, z, N, G);
    final_mlp_k<<<G, 128, 0, stream>>>(z, gx, fw1, fb1, fw2, fb2, fw3, fb3, out);
  }
}